// Round 1
// baseline (134.321 us; speedup 1.0000x reference)
//
#include <hip/hip_runtime.h>
#include <hip/hip_bf16.h>

#define NROWS 8192
#define DDIM  128
#define NCHUNK 8          // column chunks (partial-sum slots)

typedef __attribute__((ext_vector_type(8))) short short8;
typedef __attribute__((ext_vector_type(4))) float f32x4;

// ---------------- Kernel 1: row-normalize fp32 -> bf16 -------------------
// block = 256 threads = 4 waves, one row per wave, 2 elems/lane.
__global__ __launch_bounds__(256) void normalize_kernel(
    const float* __restrict__ x, __hip_bfloat16* __restrict__ q)
{
    int wave = threadIdx.x >> 6;
    int lane = threadIdx.x & 63;
    int row  = blockIdx.x * 4 + wave;
    const float* xr = x + (size_t)row * DDIM;
    float a = xr[lane];
    float b = xr[lane + 64];
    float ss = a * a + b * b;
    #pragma unroll
    for (int off = 1; off < 64; off <<= 1)
        ss += __shfl_xor(ss, off, 64);
    float rn = 1.0f / sqrtf(ss);
    q[(size_t)row * DDIM + lane]      = __float2bfloat16(a * rn);
    q[(size_t)row * DDIM + lane + 64] = __float2bfloat16(b * rn);
}

// ---------------- Kernel 2: fused QQ^T + exp + masked row-sums -----------
// grid = 1024 blocks: iblk = bid>>3 (64 rows), h = bid&7 (1024-col chunk).
// 4 waves/block, wave w owns rows [i0 + w*16, +16).
// Per 16x16 j-tile: 4 MFMA (K=128), then exp2 + masked accumulate.
__global__ __launch_bounds__(256, 4) void sim_kernel(
    const __hip_bfloat16* __restrict__ q, const int* __restrict__ y,
    float* __restrict__ topp, float* __restrict__ downp)
{
    const int bid  = blockIdx.x;
    const int iblk = bid >> 3;
    const int h    = bid & 7;
    const int wave = threadIdx.x >> 6;
    const int lane = threadIdx.x & 63;

    const int i0   = iblk * 64 + wave * 16;
    const int lrow = lane & 15;          // A row / B col within tile
    const int lk   = (lane >> 4) * 8;    // k sub-offset (8 bf16 per lane)

    const short* qs = (const short*)q;

    // A fragments for this wave's 16 rows, K = 4 slices of 32
    short8 afrag[4];
    #pragma unroll
    for (int ks = 0; ks < 4; ++ks)
        afrag[ks] = *(const short8*)(qs + (size_t)(i0 + lrow) * DDIM + ks * 32 + lk);

    // class labels for the 4 output rows this lane accumulates
    int yrow[4];
    #pragma unroll
    for (int r = 0; r < 4; ++r)
        yrow[r] = y[i0 + (lane >> 4) * 4 + r];

    float top[4]  = {0.f, 0.f, 0.f, 0.f};
    float down[4] = {0.f, 0.f, 0.f, 0.f};

    const int j0 = h * 1024;
    const float SCALE = 14.426950408889634f;  // (1/tau) * log2(e)

    for (int jt = 0; jt < 64; ++jt) {
        const int jc = j0 + jt * 16;
        short8 bfrag[4];
        #pragma unroll
        for (int ks = 0; ks < 4; ++ks)
            bfrag[ks] = *(const short8*)(qs + (size_t)(jc + lrow) * DDIM + ks * 32 + lk);
        const int ycol = y[jc + lrow];

        f32x4 acc = {0.f, 0.f, 0.f, 0.f};
        #pragma unroll
        for (int ks = 0; ks < 4; ++ks)
            acc = __builtin_amdgcn_mfma_f32_16x16x32_bf16(afrag[ks], bfrag[ks], acc, 0, 0, 0);

        #pragma unroll
        for (int r = 0; r < 4; ++r) {
            float e = __builtin_amdgcn_exp2f(acc[r] * SCALE);
            down[r] += e;
            if (yrow[r] == ycol) top[r] += e;
        }
    }

    // reduce across the 16 column-lanes (xor 1,2,4,8 stays within 16-group)
    #pragma unroll
    for (int m = 1; m < 16; m <<= 1) {
        #pragma unroll
        for (int r = 0; r < 4; ++r) {
            top[r]  += __shfl_xor(top[r],  m, 64);
            down[r] += __shfl_xor(down[r], m, 64);
        }
    }

    if ((lane & 15) == 0) {
        #pragma unroll
        for (int r = 0; r < 4; ++r) {
            int row = i0 + (lane >> 4) * 4 + r;
            topp [h * NROWS + row] = top[r];
            downp[h * NROWS + row] = down[r];
        }
    }
}

// ---------------- Kernel 3: combine partials -> mean(-log(top/down)) ----
__global__ __launch_bounds__(1024) void loss_kernel(
    const float* __restrict__ topp, const float* __restrict__ downp,
    float* __restrict__ out)
{
    __shared__ float sdata[1024];
    const int tid = threadIdx.x;
    float s = 0.f;
    for (int r = tid; r < NROWS; r += 1024) {
        float t = 0.f, d = 0.f;
        #pragma unroll
        for (int hh = 0; hh < NCHUNK; ++hh) {
            t += topp [hh * NROWS + r];
            d += downp[hh * NROWS + r];
        }
        s += __logf(d) - __logf(t);
    }
    sdata[tid] = s;
    __syncthreads();
    for (int off = 512; off > 0; off >>= 1) {
        if (tid < off) sdata[tid] += sdata[tid + off];
        __syncthreads();
    }
    if (tid == 0) out[0] = sdata[0] / (float)NROWS;
}

extern "C" void kernel_launch(void* const* d_in, const int* in_sizes, int n_in,
                              void* d_out, int out_size, void* d_ws, size_t ws_size,
                              hipStream_t stream)
{
    const float* x = (const float*)d_in[0];
    const int*   y = (const int*)d_in[1];
    float* out = (float*)d_out;

    char* ws = (char*)d_ws;
    __hip_bfloat16* q = (__hip_bfloat16*)ws;                       // 2 MB
    float* topp  = (float*)(ws + (size_t)NROWS * DDIM * 2);        // 256 KB
    float* downp = topp + NCHUNK * NROWS;                          // 256 KB

    normalize_kernel<<<NROWS / 4, 256, 0, stream>>>(x, q);
    sim_kernel<<<1024, 256, 0, stream>>>(q, y, topp, downp);
    loss_kernel<<<1, 1024, 0, stream>>>(topp, downp, out);
}

// Round 2
// 48.870 us; speedup vs baseline: 2.7485x; 2.7485x over previous
//
#include <hip/hip_runtime.h>
#include <hip/hip_bf16.h>
#include <stdint.h>

#define NROWS 8192
#define DDIM  128
#define NCHUNK 16            // column chunks (partial-sum slots)
#define ROWS_PER_BLOCK 128   // 4 waves x 32 rows
#define COLS_PER_BLOCK 512   // NROWS / NCHUNK
#define GROUP_COLS 32        // cols staged per LDS buffer
#define GROUP_BYTES (GROUP_COLS * DDIM * 2)   // 8192 B

typedef __attribute__((ext_vector_type(8))) short short8;
typedef __attribute__((ext_vector_type(4))) float f32x4;

__device__ __forceinline__ void load_lds16(const void* g, void* l) {
    __builtin_amdgcn_global_load_lds(
        (const __attribute__((address_space(1))) void*)g,
        (__attribute__((address_space(3))) void*)l, 16, 0, 0);
}

// ---------------- Kernel 1: row-normalize fp32 -> bf16 -------------------
__global__ __launch_bounds__(256) void normalize_kernel(
    const float* __restrict__ x, __hip_bfloat16* __restrict__ q)
{
    int wave = threadIdx.x >> 6;
    int lane = threadIdx.x & 63;
    int row  = blockIdx.x * 4 + wave;
    const float* xr = x + (size_t)row * DDIM;
    float a = xr[lane];
    float b = xr[lane + 64];
    float ss = a * a + b * b;
    #pragma unroll
    for (int off = 1; off < 64; off <<= 1)
        ss += __shfl_xor(ss, off, 64);
    float rn = 1.0f / sqrtf(ss);
    q[(size_t)row * DDIM + lane]      = __float2bfloat16(a * rn);
    q[(size_t)row * DDIM + lane + 64] = __float2bfloat16(b * rn);
}

// ---------------- Kernel 2: fused QQ^T + exp + masked row-sums -----------
// grid = 64 row-blocks x 16 col-chunks. Block: 4 waves, 128 rows x 512 cols.
// Wave w owns rows [iblk*128 + w*32, +32) (2 row-tiles of 16).
// B staged in LDS in 32-col groups, double-buffered, XOR-swizzled.
__global__ __launch_bounds__(256, 4) void sim_kernel(
    const __hip_bfloat16* __restrict__ q, const int* __restrict__ y,
    float* __restrict__ topp, float* __restrict__ downp)
{
    __shared__ char smem[2 * GROUP_BYTES];

    const int bid  = blockIdx.x;
    const int iblk = bid >> 4;
    const int h    = bid & 15;
    const int tid  = threadIdx.x;
    const int wave = tid >> 6;
    const int lane = tid & 63;
    const int lrow = lane & 15;
    const int lhi  = lane >> 4;

    const char* qb = (const char*)q;
    const int rbase = iblk * ROWS_PER_BLOCK + wave * 32;
    const int jbase = h * COLS_PER_BLOCK;

    // A fragments: 2 row-tiles x 4 K-slices (32 VGPRs), loaded once.
    short8 afrag[2][4];
    #pragma unroll
    for (int t = 0; t < 2; ++t)
        #pragma unroll
        for (int ks = 0; ks < 4; ++ks)
            afrag[t][ks] = *(const short8*)(qb +
                (size_t)(rbase + t * 16 + lrow) * 256 + ks * 64 + lhi * 16);

    int yrow[2][4];
    #pragma unroll
    for (int t = 0; t < 2; ++t)
        #pragma unroll
        for (int r = 0; r < 4; ++r)
            yrow[t][r] = y[rbase + t * 16 + lhi * 4 + r];

    float top[2][4]  = {{0.f,0.f,0.f,0.f},{0.f,0.f,0.f,0.f}};
    float down[2][4] = {{0.f,0.f,0.f,0.f},{0.f,0.f,0.f,0.f}};

    const float SCALE = 14.426950408889634f;  // (1/tau) * log2(e)
    const int NGROUPS = COLS_PER_BLOCK / GROUP_COLS;  // 16

    // stage group g into buffer buf (linear dest, inverse-swizzled source)
    auto stage = [&](int buf, int g) {
        const int jstart = jbase + g * GROUP_COLS;
        #pragma unroll
        for (int p = 0; p < 2; ++p) {
            int phys = p * 4096 + wave * 1024 + lane * 16;
            int L = phys ^ (((phys >> 8) & 7) << 4);
            const char* src = qb + (size_t)(jstart + (L >> 8)) * 256 + (L & 255);
            load_lds16(src, smem + buf * GROUP_BYTES + p * 4096 + wave * 1024);
        }
    };

    stage(0, 0);
    __syncthreads();

    for (int g = 0; g < NGROUPS; ++g) {
        if (g + 1 < NGROUPS) stage((g + 1) & 1, g + 1);

        const char* lbuf = smem + (g & 1) * GROUP_BYTES;
        const int jc0 = jbase + g * GROUP_COLS;

        #pragma unroll
        for (int jt = 0; jt < 2; ++jt) {
            const int cg = jt * 16 + lrow;
            const int ycol = y[jc0 + cg];
            short8 bfrag[4];
            #pragma unroll
            for (int ks = 0; ks < 4; ++ks) {
                int L = cg * 256 + ks * 64 + lhi * 16;
                int phys = L ^ ((cg & 7) << 4);
                bfrag[ks] = *(const short8*)(lbuf + phys);
            }
            #pragma unroll
            for (int t = 0; t < 2; ++t) {
                f32x4 acc = {0.f, 0.f, 0.f, 0.f};
                #pragma unroll
                for (int ks = 0; ks < 4; ++ks)
                    acc = __builtin_amdgcn_mfma_f32_16x16x32_bf16(
                        afrag[t][ks], bfrag[ks], acc, 0, 0, 0);
                #pragma unroll
                for (int r = 0; r < 4; ++r) {
                    float e = __builtin_amdgcn_exp2f(acc[r] * SCALE);
                    down[t][r] += e;
                    if (yrow[t][r] == ycol) top[t][r] += e;
                }
            }
        }
        __syncthreads();
    }

    // reduce across the 16 column-lanes of each group
    #pragma unroll
    for (int m = 1; m < 16; m <<= 1) {
        #pragma unroll
        for (int t = 0; t < 2; ++t)
            #pragma unroll
            for (int r = 0; r < 4; ++r) {
                top[t][r]  += __shfl_xor(top[t][r],  m, 64);
                down[t][r] += __shfl_xor(down[t][r], m, 64);
            }
    }

    if (lrow == 0) {
        #pragma unroll
        for (int t = 0; t < 2; ++t)
            #pragma unroll
            for (int r = 0; r < 4; ++r) {
                int row = rbase + t * 16 + lhi * 4 + r;
                topp [h * NROWS + row] = top[t][r];
                downp[h * NROWS + row] = down[t][r];
            }
    }
}

// ---------------- Kernel 3: combine partials -> mean(-log(top/down)) ----
__global__ __launch_bounds__(1024) void loss_kernel(
    const float* __restrict__ topp, const float* __restrict__ downp,
    float* __restrict__ out)
{
    __shared__ float sdata[1024];
    const int tid = threadIdx.x;
    float s = 0.f;
    for (int r = tid; r < NROWS; r += 1024) {
        float t = 0.f, d = 0.f;
        #pragma unroll
        for (int hh = 0; hh < NCHUNK; ++hh) {
            t += topp [hh * NROWS + r];
            d += downp[hh * NROWS + r];
        }
        s += __logf(d) - __logf(t);
    }
    sdata[tid] = s;
    __syncthreads();
    for (int off = 512; off > 0; off >>= 1) {
        if (tid < off) sdata[tid] += sdata[tid + off];
        __syncthreads();
    }
    if (tid == 0) out[0] = sdata[0] / (float)NROWS;
}

extern "C" void kernel_launch(void* const* d_in, const int* in_sizes, int n_in,
                              void* d_out, int out_size, void* d_ws, size_t ws_size,
                              hipStream_t stream)
{
    const float* x = (const float*)d_in[0];
    const int*   y = (const int*)d_in[1];
    float* out = (float*)d_out;

    char* ws = (char*)d_ws;
    __hip_bfloat16* q = (__hip_bfloat16*)ws;                       // 2 MB
    float* topp  = (float*)(ws + (size_t)NROWS * DDIM * 2);        // 512 KB
    float* downp = topp + NCHUNK * NROWS;                          // 512 KB

    normalize_kernel<<<NROWS / 4, 256, 0, stream>>>(x, q);
    sim_kernel<<<64 * NCHUNK, 256, 0, stream>>>(q, y, topp, downp);
    loss_kernel<<<1, 1024, 0, stream>>>(topp, downp, out);
}

// Round 3
// 41.738 us; speedup vs baseline: 3.2182x; 1.1709x over previous
//
#include <hip/hip_runtime.h>
#include <hip/hip_bf16.h>
#include <stdint.h>

#define NROWS 8192
#define DDIM  128
#define NCHUNK 16            // column chunks (partial-sum slots)
#define ROWS_PER_BLOCK 128   // 4 waves x 32 rows
#define COLS_PER_BLOCK 512   // NROWS / NCHUNK
#define GROUP_COLS 64        // cols staged per LDS buffer
#define GROUP_BYTES (GROUP_COLS * DDIM * 2)   // 16384 B
#define NGROUPS (COLS_PER_BLOCK / GROUP_COLS) // 8

typedef __attribute__((ext_vector_type(8))) short short8;
typedef __attribute__((ext_vector_type(4))) float f32x4;

__device__ __forceinline__ void load_lds16(const void* g, void* l) {
    __builtin_amdgcn_global_load_lds(
        (const __attribute__((address_space(1))) void*)g,
        (__attribute__((address_space(3))) void*)l, 16, 0, 0);
}

// (1/tau) * log2(e); q is pre-scaled by sqrt of this so exp2(acc) is direct.
#define SCALE 14.426950408889634f

// ---------------- Kernel 1: row-normalize fp32 -> scaled bf16 ------------
__global__ __launch_bounds__(256) void normalize_kernel(
    const float* __restrict__ x, __hip_bfloat16* __restrict__ q)
{
    int wave = threadIdx.x >> 6;
    int lane = threadIdx.x & 63;
    int row  = blockIdx.x * 4 + wave;
    const float* xr = x + (size_t)row * DDIM;
    float a = xr[lane];
    float b = xr[lane + 64];
    float ss = a * a + b * b;
    #pragma unroll
    for (int off = 1; off < 64; off <<= 1)
        ss += __shfl_xor(ss, off, 64);
    float rn = sqrtf(SCALE) / sqrtf(ss);   // fold exp2 scale into q
    q[(size_t)row * DDIM + lane]      = __float2bfloat16(a * rn);
    q[(size_t)row * DDIM + lane + 64] = __float2bfloat16(b * rn);
}

// ---------------- Kernel 2: fused QQ^T + exp + masked row-sums -----------
// grid = 64 row-blocks x 16 col-chunks. Block: 4 waves, 128 rows x 512 cols.
// B staged in LDS in 64-col groups, double-buffered, XOR-swizzled (T2/T21).
__global__ __launch_bounds__(256, 4) void sim_kernel(
    const __hip_bfloat16* __restrict__ q, const int* __restrict__ y,
    float* __restrict__ topp, float* __restrict__ downp)
{
    __shared__ char smem[2 * GROUP_BYTES];
    __shared__ int  yl[COLS_PER_BLOCK];

    const int bid  = blockIdx.x;
    const int iblk = bid >> 4;
    const int h    = bid & 15;
    const int tid  = threadIdx.x;
    const int wave = tid >> 6;
    const int lane = tid & 63;
    const int lrow = lane & 15;
    const int lhi  = lane >> 4;

    const char* qb = (const char*)q;
    const int rbase = iblk * ROWS_PER_BLOCK + wave * 32;
    const int jbase = h * COLS_PER_BLOCK;

    // stage this chunk's labels into LDS once
    yl[tid]       = y[jbase + tid];
    yl[tid + 256] = y[jbase + tid + 256];

    // A fragments: 2 row-tiles x 4 K-slices (32 VGPRs), loaded once.
    short8 afrag[2][4];
    #pragma unroll
    for (int t = 0; t < 2; ++t)
        #pragma unroll
        for (int ks = 0; ks < 4; ++ks)
            afrag[t][ks] = *(const short8*)(qb +
                (size_t)(rbase + t * 16 + lrow) * 256 + ks * 64 + lhi * 16);

    int yrow[2][4];
    #pragma unroll
    for (int t = 0; t < 2; ++t)
        #pragma unroll
        for (int r = 0; r < 4; ++r)
            yrow[t][r] = y[rbase + t * 16 + lhi * 4 + r];

    float top[2][4]  = {{0.f,0.f,0.f,0.f},{0.f,0.f,0.f,0.f}};
    float down[2][4] = {{0.f,0.f,0.f,0.f},{0.f,0.f,0.f,0.f}};

    // stage group g into buffer buf (linear dest, inverse-swizzled source)
    auto stage = [&](int buf, int g) {
        const int jstart = jbase + g * GROUP_COLS;
        #pragma unroll
        for (int p = 0; p < 4; ++p) {
            int phys = p * 4096 + wave * 1024 + lane * 16;
            int L = phys ^ (((phys >> 8) & 7) << 4);
            const char* src = qb + (size_t)(jstart + (L >> 8)) * 256 + (L & 255);
            load_lds16(src, smem + buf * GROUP_BYTES + p * 4096 + wave * 1024);
        }
    };

    stage(0, 0);
    __syncthreads();

    for (int g = 0; g < NGROUPS; ++g) {
        if (g + 1 < NGROUPS) stage((g + 1) & 1, g + 1);

        const char* lbuf = smem + (g & 1) * GROUP_BYTES;

        #pragma unroll
        for (int jt = 0; jt < 4; ++jt) {
            const int cg = jt * 16 + lrow;
            const int ycol = yl[g * GROUP_COLS + cg];
            short8 bfrag[4];
            #pragma unroll
            for (int ks = 0; ks < 4; ++ks) {
                int L = cg * 256 + ks * 64 + lhi * 16;
                int phys = L ^ ((cg & 7) << 4);
                bfrag[ks] = *(const short8*)(lbuf + phys);
            }
            #pragma unroll
            for (int t = 0; t < 2; ++t) {
                f32x4 acc = {0.f, 0.f, 0.f, 0.f};
                #pragma unroll
                for (int ks = 0; ks < 4; ++ks)
                    acc = __builtin_amdgcn_mfma_f32_16x16x32_bf16(
                        afrag[t][ks], bfrag[ks], acc, 0, 0, 0);
                #pragma unroll
                for (int r = 0; r < 4; ++r) {
                    float e = __builtin_amdgcn_exp2f(acc[r]);
                    down[t][r] += e;
                    if (yrow[t][r] == ycol) top[t][r] += e;
                }
            }
        }
        __syncthreads();
    }

    // reduce across the 16 column-lanes of each group
    #pragma unroll
    for (int m = 1; m < 16; m <<= 1) {
        #pragma unroll
        for (int t = 0; t < 2; ++t)
            #pragma unroll
            for (int r = 0; r < 4; ++r) {
                top[t][r]  += __shfl_xor(top[t][r],  m, 64);
                down[t][r] += __shfl_xor(down[t][r], m, 64);
            }
    }

    if (lrow == 0) {
        #pragma unroll
        for (int t = 0; t < 2; ++t)
            #pragma unroll
            for (int r = 0; r < 4; ++r) {
                int row = rbase + t * 16 + lhi * 4 + r;
                topp [h * NROWS + row] = top[t][r];
                downp[h * NROWS + row] = down[t][r];
            }
    }
}

// ---------------- Kernel 3a: per-row loss, 128-block partial reduce ------
__global__ __launch_bounds__(64) void loss_partial_kernel(
    const float* __restrict__ topp, const float* __restrict__ downp,
    float* __restrict__ partial)
{
    const int lane = threadIdx.x;
    const int r = blockIdx.x * 64 + lane;
    float t = 0.f, d = 0.f;
    #pragma unroll
    for (int hh = 0; hh < NCHUNK; ++hh) {
        t += topp [hh * NROWS + r];
        d += downp[hh * NROWS + r];
    }
    float s = __logf(d) - __logf(t);
    #pragma unroll
    for (int off = 1; off < 64; off <<= 1)
        s += __shfl_xor(s, off, 64);
    if (lane == 0) partial[blockIdx.x] = s;
}

// ---------------- Kernel 3b: final 128 -> scalar -------------------------
__global__ __launch_bounds__(64) void loss_final_kernel(
    const float* __restrict__ partial, float* __restrict__ out)
{
    const int lane = threadIdx.x;
    float s = partial[lane] + partial[lane + 64];
    #pragma unroll
    for (int off = 1; off < 64; off <<= 1)
        s += __shfl_xor(s, off, 64);
    if (lane == 0) out[0] = s / (float)NROWS;
}

extern "C" void kernel_launch(void* const* d_in, const int* in_sizes, int n_in,
                              void* d_out, int out_size, void* d_ws, size_t ws_size,
                              hipStream_t stream)
{
    const float* x = (const float*)d_in[0];
    const int*   y = (const int*)d_in[1];
    float* out = (float*)d_out;

    char* ws = (char*)d_ws;
    __hip_bfloat16* q = (__hip_bfloat16*)ws;                       // 2 MB
    float* topp  = (float*)(ws + (size_t)NROWS * DDIM * 2);        // 512 KB
    float* downp = topp + NCHUNK * NROWS;                          // 512 KB
    float* partial = downp + NCHUNK * NROWS;                       // 512 B

    normalize_kernel<<<NROWS / 4, 256, 0, stream>>>(x, q);
    sim_kernel<<<64 * NCHUNK, 256, 0, stream>>>(q, y, topp, downp);
    loss_partial_kernel<<<NROWS / 64, 64, 0, stream>>>(topp, downp, partial);
    loss_final_kernel<<<1, 64, 0, stream>>>(partial, out);
}